// Round 12
// baseline (445.243 us; speedup 1.0000x reference)
//
#include <hip/hip_runtime.h>

#define NN 100000
#define NE 600000
#define FD 128                       // feature dim of h (in & hidden)
#define NB ((NN + 255) / 256)        // 391 scan blocks
#define NTILES ((NN + 63) / 64)      // 1563 row tiles

typedef __attribute__((ext_vector_type(8))) short bf16x8;
typedef __attribute__((ext_vector_type(4))) float f32x4;

__device__ __forceinline__ unsigned short f2bf(float x) {
    unsigned int u = __float_as_uint(x);
    u += 0x7FFFu + ((u >> 16) & 1u);          // RNE
    return (unsigned short)(u >> 16);
}

// ================= CSR build (by destination) =================
__global__ __launch_bounds__(256) void hist_kernel(const int* __restrict__ dst,
                                                   int* __restrict__ cnt, int E) {
    int e = blockIdx.x * 256 + threadIdx.x;
    if (e < E) atomicAdd(&cnt[dst[e]], 1);
}

__global__ __launch_bounds__(256) void scan_blocks(const int* __restrict__ cnt,
                                                   int* __restrict__ bsum) {
    __shared__ int s[256];
    int i = blockIdx.x * 256 + threadIdx.x;
    int t = threadIdx.x;
    s[t] = (i < NN) ? cnt[i] : 0;
    __syncthreads();
    for (int off = 128; off > 0; off >>= 1) {
        if (t < off) s[t] += s[t + off];
        __syncthreads();
    }
    if (t == 0) bsum[blockIdx.x] = s[0];
}

__global__ __launch_bounds__(512) void scan_top(int* __restrict__ bsum,
                                                int* __restrict__ row_ptr) {
    __shared__ int s[512];
    int t = threadIdx.x;
    int v = (t < NB) ? bsum[t] : 0;
    s[t] = v;
    __syncthreads();
    for (int off = 1; off < 512; off <<= 1) {
        int x = (t >= off) ? s[t - off] : 0;
        __syncthreads();
        s[t] += x;
        __syncthreads();
    }
    if (t < NB) bsum[t] = s[t] - v;          // exclusive block offsets
    if (t == 0) row_ptr[NN] = NE;
}

__global__ __launch_bounds__(256) void scan_write(const int* __restrict__ cnt,
                                                  const int* __restrict__ bofs,
                                                  int* __restrict__ row_ptr) {
    __shared__ int s[256];
    int i = blockIdx.x * 256 + threadIdx.x;
    int t = threadIdx.x;
    int v = (i < NN) ? cnt[i] : 0;
    s[t] = v;
    __syncthreads();
    for (int off = 1; off < 256; off <<= 1) {
        int x = (t >= off) ? s[t - off] : 0;
        __syncthreads();
        s[t] += x;
        __syncthreads();
    }
    if (i < NN) row_ptr[i] = s[t] - v + bofs[blockIdx.x];
}

__global__ __launch_bounds__(256) void fill_kernel(const int* __restrict__ src,
                                                   const int* __restrict__ dst,
                                                   int* __restrict__ cursor,
                                                   int* __restrict__ col, int E) {
    int e = blockIdx.x * 256 + threadIdx.x;
    if (e < E) {
        int p = atomicAdd(&cursor[dst[e]], 1);
        col[p] = src[e];
    }
}

// ================= f32 -> bf16 conversion (x once per call) =================
__global__ __launch_bounds__(256) void cvt_kernel(const float* __restrict__ x,
                                                  unsigned short* __restrict__ xb,
                                                  int n4) {
    int i = blockIdx.x * 256 + threadIdx.x;
    if (i < n4) {
        float4 v = reinterpret_cast<const float4*>(x)[i];
        uint2 o;
        o.x = (unsigned)f2bf(v.x) | ((unsigned)f2bf(v.y) << 16);
        o.y = (unsigned)f2bf(v.z) | ((unsigned)f2bf(v.w) << 16);
        reinterpret_cast<uint2*>(xb)[i] = o;
    }
}

// ================= weight pre-convert: Wb[j][0:256] = bf16([Ws|Wn][j]) ======
__global__ __launch_bounds__(256) void wcvt_kernel(const float* __restrict__ Ws,
                                                   const float* __restrict__ Wn,
                                                   unsigned short* __restrict__ Wb,
                                                   int rows) {
    int tid = blockIdx.x * 256 + threadIdx.x;
    if (tid >= rows * 64) return;
    int row = tid >> 6;
    int k   = (tid & 63) * 4;                 // chunk of 4, never straddles 128
    const float* src = (k < 128) ? (Ws + (size_t)row * 128 + k)
                                 : (Wn + (size_t)row * 128 + (k - 128));
    float4 v = *reinterpret_cast<const float4*>(src);
    uint2 o;
    o.x = (unsigned)f2bf(v.x) | ((unsigned)f2bf(v.y) << 16);
    o.y = (unsigned)f2bf(v.z) | ((unsigned)f2bf(v.w) << 16);
    *reinterpret_cast<uint2*>(Wb + (size_t)row * 256 + k) = o;
}

// ================= gather-mean aggregation (bf16 in/out, f32 accum) =========
// one wave per dst node; lane l holds features [2l, 2l+1] (4B packed bf16x2).
// R10: MLP=4 unroll cut 67.5->~38us (latency-bound). R12: 8 clamped-index
// streams (idx=min(e+i,last), value zero-masked) — no tail branches, MLP=8.
__device__ __forceinline__ void bf2_acc(unsigned v, float& ax, float& ay) {
    ax += __uint_as_float(v << 16);
    ay += __uint_as_float(v & 0xFFFF0000u);
}

__global__ __launch_bounds__(256) void agg_kernel(const unsigned short* __restrict__ h,
                                                  const int* __restrict__ rp,
                                                  const int* __restrict__ col,
                                                  unsigned short* __restrict__ agg) {
    int w    = (blockIdx.x * 256 + threadIdx.x) >> 6;
    int lane = threadIdx.x & 63;
    if (w >= NN) return;
    int beg = __builtin_amdgcn_readfirstlane(rp[w]);
    int end = __builtin_amdgcn_readfirstlane(rp[w + 1]);
    const unsigned short* hl = h + lane * 2;
    float ax = 0.f, ay = 0.f;
    if (beg < end) {
        int last = end - 1;
        for (int e = beg; e < end; e += 8) {
#pragma unroll
            for (int i = 0; i < 8; ++i) {
                int ee  = e + i;
                int idx = col[ee <= last ? ee : last];
                unsigned v = *reinterpret_cast<const unsigned*>(hl + (size_t)idx * FD);
                if (ee > last) v = 0u;
                bf2_acc(v, ax, ay);
            }
        }
    }
    float inv = 1.0f / fmaxf((float)(end - beg), 1.0f);
    ax *= inv;
    ay *= inv;
    *reinterpret_cast<unsigned*>(agg + (size_t)w * FD + lane * 2) =
        (unsigned)f2bf(ax) | ((unsigned)f2bf(ay) << 16);
}

// ================= persistent MFMA SAGE GEMM (v3) =================
// R11 PMC: MfmaUtil 5.5 / VALU 9 / HBM 16 / Occ 20 — pure staging latency;
// B (64KB) re-staged by all 1563 blocks (100MB L2 traffic).
// v3: grid=512 persistent blocks, 2 blocks/CU (LDS 64KB). Each block owns a
// 64-col B slice (32KB LDS, staged ONCE) and grid-strides row-tiles.
// A double-buffered 2x16KB half-K tiles; per half: {ds_write regs, barrier,
// issue next-half global loads (after barrier so its full drain doesn't eat
// them), 16 MFMA/wave, epilogue on kc=1}. One barrier per half-tile; load
// latency hides under the co-resident block's compute (m114 overlap).
// XOR swizzle byte^=(row&7)<<4 on both ds_write and ds_read sides.
template <int CT, bool RELU, bool OUTBF16, int OSTRIDE>
__global__ __launch_bounds__(256, 2) void mfma_gemm(const unsigned short* __restrict__ Ah,
                                                    const unsigned short* __restrict__ Ag,
                                                    const unsigned short* __restrict__ Wb,
                                                    const float* __restrict__ bias,
                                                    void* __restrict__ outp, int N) {
    __shared__ char lds[65536];               // A: 2x16KB @0, B: 32KB @32768
    char* Bl = lds + 32768;

    const int t       = threadIdx.x;
    const int bid     = blockIdx.x;
    const int colhalf = (CT == 2) ? (bid & 1) : 0;
    const int tstart  = (CT == 2) ? (bid >> 1) : bid;
    const int tstride = gridDim.x / CT;       // 256 (CT=2) or 512 (CT=1)
    const int jbase   = colhalf * 64;

    const int w   = t >> 6;
    const int l   = t & 63;
    const int lo4 = l & 15;
    const int hi  = l >> 4;
    const int xr  = (lo4 & 7) << 4;

    // ---- stage B once: 64 rows x 256 k (512B rows), swizzled ----
    {
        uint4 r[8];
#pragma unroll
        for (int p = 0; p < 8; ++p) {
            int c = t + p * 256;              // 0..2047
            int row = c >> 5, ch = c & 31;
            r[p] = *reinterpret_cast<const uint4*>(
                Wb + (size_t)(jbase + row) * 256 + ch * 8);
        }
#pragma unroll
        for (int p = 0; p < 8; ++p) {
            int c = t + p * 256;
            int row = c >> 5, ch = c & 31;
            *reinterpret_cast<uint4*>(
                Bl + ((row * 512 + ch * 16) ^ ((row & 7) << 4))) = r[p];
        }
    }

    // per-thread A chunk geometry: c = t + p*256 -> row=c>>4, ch=c&15
    uint4 ar[4];
    auto A_LOAD = [&](int tl, int kc) {
        const unsigned short* As = kc ? Ag : Ah;
#pragma unroll
        for (int p = 0; p < 4; ++p) {
            int c = t + p * 256;              // 0..1023
            int row = c >> 4, ch = c & 15;
            int n = tl * 64 + row;
            if (n >= N) n = N - 1;            // clamp; stores are guarded
            ar[p] = *reinterpret_cast<const uint4*>(As + (size_t)n * FD + ch * 8);
        }
    };
    auto A_WRITE = [&](int buf) {
        char* Ab = lds + buf * 16384;
#pragma unroll
        for (int p = 0; p < 4; ++p) {
            int c = t + p * 256;
            int row = c >> 4, ch = c & 15;
            *reinterpret_cast<uint4*>(
                Ab + ((row * 256 + ch * 16) ^ ((row & 7) << 4))) = ar[p];
        }
    };

    f32x4 acc[4];
#pragma unroll
    for (int f = 0; f < 4; ++f) acc[f] = {0.f, 0.f, 0.f, 0.f};

    const int mytiles = (NTILES - 1 - tstart) / tstride + 1;   // tstart<512<NTILES
    const int total   = mytiles * 2;                           // half-tiles

    unsigned short* hout = (unsigned short*)outp;
    float* fout = (float*)outp;

    A_LOAD(tstart, 0);
    for (int i = 0; i < total; ++i) {
        const int b  = i & 1;
        const int kc = i & 1;                  // halves alternate kc (2 per tile)
        A_WRITE(b);
        __syncthreads();                       // buf b ready (drains everything)
        if (i + 1 < total) {                   // issue next-half loads AFTER bar
            int ni = i + 1;
            A_LOAD(tstart + (ni >> 1) * tstride, ni & 1);
        }
        const char* Arow = lds + b * 16384 + (w * 16 + lo4) * 256;
#pragma unroll
        for (int ks = 0; ks < 4; ++ks) {
            int akoff = (ks * 64 + hi * 16) ^ xr;
            bf16x8 a = *reinterpret_cast<const bf16x8*>(Arow + akoff);
#pragma unroll
            for (int f = 0; f < 4; ++f) {
                int brow = f * 16 + lo4;
                int bk   = (kc * 256 + ks * 64 + hi * 16) ^ ((brow & 7) << 4);
                bf16x8 bb = *reinterpret_cast<const bf16x8*>(Bl + brow * 512 + bk);
                acc[f] = __builtin_amdgcn_mfma_f32_16x16x32_bf16(a, bb, acc[f], 0, 0, 0);
            }
        }
        if (kc == 1) {
            // epilogue: C/D map col=l&15, row=(l>>4)*4+reg (m89)
            int tl    = tstart + (i >> 1) * tstride;
            int rbase = tl * 64 + w * 16 + hi * 4;
#pragma unroll
            for (int f = 0; f < 4; ++f) {
                int col  = jbase + f * 16 + lo4;
                float bv = bias[col];
#pragma unroll
                for (int r = 0; r < 4; ++r) {
                    int n = rbase + r;
                    if (n < N) {
                        float v = acc[f][r] + bv;
                        if (RELU) v = fmaxf(v, 0.f);
                        if (OUTBF16) hout[(size_t)n * OSTRIDE + col] = f2bf(v);
                        else         fout[(size_t)n * OSTRIDE + col] = v;
                    }
                }
                acc[f] = {0.f, 0.f, 0.f, 0.f};
            }
        }
        // next iteration's A_WRITE(b^1) is safe: its last readers (MFMA i-1)
        // finished before this iteration's barrier.
    }
}

extern "C" void kernel_launch(void* const* d_in, const int* in_sizes, int n_in,
                              void* d_out, int out_size, void* d_ws, size_t ws_size,
                              hipStream_t stream) {
    const float* x        = (const float*)d_in[0];
    const int*   edge_src = (const int*)d_in[1];
    const int*   edge_dst = (const int*)d_in[2];
    const float* Ws1 = (const float*)d_in[3];
    const float* Wn1 = (const float*)d_in[4];
    const float* b1  = (const float*)d_in[5];
    const float* Ws2 = (const float*)d_in[6];
    const float* Wn2 = (const float*)d_in[7];
    const float* b2  = (const float*)d_in[8];
    const float* Ws3 = (const float*)d_in[9];
    const float* Wn3 = (const float*)d_in[10];
    const float* b3  = (const float*)d_in[11];
    float* out = (float*)d_out;

    // ---- memory plan (d_ws == proven-safe 102.8 MB footprint) ----
    // d_ws : x_bf16 | h_a | h_b | agg (each NN*FD bf16 = 25.6MB) | cursor
    // d_out: col_src [NE] | row_ptr [NN+1] | pad | Wb1 | Wb2  (all reads
    //        complete before the final GEMM overwrites d_out)
    // Wb3 -> cursor region (dead after fill_kernel; wcvt3 runs after fill).
    // bsum aliases agg head (dead until first agg_kernel).
    unsigned short* x_bf = (unsigned short*)d_ws;
    unsigned short* h_a  = x_bf + (size_t)NN * FD;
    unsigned short* h_b  = h_a + (size_t)NN * FD;
    unsigned short* aggb = h_b + (size_t)NN * FD;
    int* cursor = (int*)(aggb + (size_t)NN * FD);
    int* bsum   = (int*)aggb;
    int* col_src = (int*)d_out;
    int* row_ptr = col_src + NE;
    unsigned short* wb1 = (unsigned short*)(col_src + NE + NN + 4);  // 16B-aligned
    unsigned short* wb2 = wb1 + 128 * 256;
    unsigned short* wb3 = (unsigned short*)cursor;                   // after fill

    const int edgeGrid = (NE + 255) / 256;
    const int aggGrid  = NN / 4;                         // 4 waves/block

    // ---- x -> bf16; weights -> packed bf16 ----
    cvt_kernel<<<(NN * FD / 4 + 255) / 256, 256, 0, stream>>>(x, x_bf, NN * FD / 4);
    wcvt_kernel<<<32, 256, 0, stream>>>(Ws1, Wn1, wb1, 128);
    wcvt_kernel<<<32, 256, 0, stream>>>(Ws2, Wn2, wb2, 128);

    // ---- CSR build ----
    hipMemsetAsync(cursor, 0, (size_t)NN * sizeof(int), stream);
    hist_kernel<<<edgeGrid, 256, 0, stream>>>(edge_dst, cursor, NE);
    scan_blocks<<<NB, 256, 0, stream>>>(cursor, bsum);
    scan_top<<<1, 512, 0, stream>>>(bsum, row_ptr);
    scan_write<<<NB, 256, 0, stream>>>(cursor, bsum, row_ptr);
    hipMemcpyAsync(cursor, row_ptr, (size_t)NN * sizeof(int),
                   hipMemcpyDeviceToDevice, stream);
    fill_kernel<<<edgeGrid, 256, 0, stream>>>(edge_src, edge_dst, cursor,
                                              col_src, NE);
    wcvt_kernel<<<16, 256, 0, stream>>>(Ws3, Wn3, wb3, 64);  // cursor now dead

    // ---- layer 1: x_bf -> h_a ----
    agg_kernel<<<aggGrid, 256, 0, stream>>>(x_bf, row_ptr, col_src, aggb);
    mfma_gemm<2, true, true, 128><<<512, 256, 0, stream>>>(
        x_bf, aggb, wb1, b1, h_a, NN);

    // ---- layer 2: h_a -> h_b ----
    agg_kernel<<<aggGrid, 256, 0, stream>>>(h_a, row_ptr, col_src, aggb);
    mfma_gemm<2, true, true, 128><<<512, 256, 0, stream>>>(
        h_a, aggb, wb2, b2, h_b, NN);

    // ---- layer 3: h_b -> out (f32, no ReLU; overwrites CSR+Wb in d_out) ----
    agg_kernel<<<aggGrid, 256, 0, stream>>>(h_b, row_ptr, col_src, aggb);
    mfma_gemm<1, false, false, 64><<<512, 256, 0, stream>>>(
        h_b, aggb, wb3, b3, out, NN);
}

// Round 13
// 365.961 us; speedup vs baseline: 1.2166x; 1.2166x over previous
//
#include <hip/hip_runtime.h>

#define NN 100000
#define NE 600000
#define FD 128                       // feature dim of h (in & hidden)
#define NB ((NN + 255) / 256)        // 391 scan blocks

typedef __attribute__((ext_vector_type(8))) short bf16x8;
typedef __attribute__((ext_vector_type(4))) float f32x4;

__device__ __forceinline__ unsigned short f2bf(float x) {
    unsigned int u = __float_as_uint(x);
    u += 0x7FFFu + ((u >> 16) & 1u);          // RNE
    return (unsigned short)(u >> 16);
}

// ================= CSR build (by destination) =================
__global__ __launch_bounds__(256) void hist_kernel(const int* __restrict__ dst,
                                                   int* __restrict__ cnt, int E) {
    int e = blockIdx.x * 256 + threadIdx.x;
    if (e < E) atomicAdd(&cnt[dst[e]], 1);
}

__global__ __launch_bounds__(256) void scan_blocks(const int* __restrict__ cnt,
                                                   int* __restrict__ bsum) {
    __shared__ int s[256];
    int i = blockIdx.x * 256 + threadIdx.x;
    int t = threadIdx.x;
    s[t] = (i < NN) ? cnt[i] : 0;
    __syncthreads();
    for (int off = 128; off > 0; off >>= 1) {
        if (t < off) s[t] += s[t + off];
        __syncthreads();
    }
    if (t == 0) bsum[blockIdx.x] = s[0];
}

__global__ __launch_bounds__(512) void scan_top(int* __restrict__ bsum,
                                                int* __restrict__ row_ptr) {
    __shared__ int s[512];
    int t = threadIdx.x;
    int v = (t < NB) ? bsum[t] : 0;
    s[t] = v;
    __syncthreads();
    for (int off = 1; off < 512; off <<= 1) {
        int x = (t >= off) ? s[t - off] : 0;
        __syncthreads();
        s[t] += x;
        __syncthreads();
    }
    if (t < NB) bsum[t] = s[t] - v;          // exclusive block offsets
    if (t == 0) row_ptr[NN] = NE;
}

__global__ __launch_bounds__(256) void scan_write(const int* __restrict__ cnt,
                                                  const int* __restrict__ bofs,
                                                  int* __restrict__ row_ptr) {
    __shared__ int s[256];
    int i = blockIdx.x * 256 + threadIdx.x;
    int t = threadIdx.x;
    int v = (i < NN) ? cnt[i] : 0;
    s[t] = v;
    __syncthreads();
    for (int off = 1; off < 256; off <<= 1) {
        int x = (t >= off) ? s[t - off] : 0;
        __syncthreads();
        s[t] += x;
        __syncthreads();
    }
    if (i < NN) row_ptr[i] = s[t] - v + bofs[blockIdx.x];
}

__global__ __launch_bounds__(256) void fill_kernel(const int* __restrict__ src,
                                                   const int* __restrict__ dst,
                                                   int* __restrict__ cursor,
                                                   int* __restrict__ col, int E) {
    int e = blockIdx.x * 256 + threadIdx.x;
    if (e < E) {
        int p = atomicAdd(&cursor[dst[e]], 1);
        col[p] = src[e];
    }
}

// ================= f32 -> bf16 conversion (x once per call) =================
__global__ __launch_bounds__(256) void cvt_kernel(const float* __restrict__ x,
                                                  unsigned short* __restrict__ xb,
                                                  int n4) {
    int i = blockIdx.x * 256 + threadIdx.x;
    if (i < n4) {
        float4 v = reinterpret_cast<const float4*>(x)[i];
        uint2 o;
        o.x = (unsigned)f2bf(v.x) | ((unsigned)f2bf(v.y) << 16);
        o.y = (unsigned)f2bf(v.z) | ((unsigned)f2bf(v.w) << 16);
        reinterpret_cast<uint2*>(xb)[i] = o;
    }
}

// ================= weight pre-convert: Wb[j][0:256] = bf16([Ws|Wn][j]) ======
__global__ __launch_bounds__(256) void wcvt_kernel(const float* __restrict__ Ws,
                                                   const float* __restrict__ Wn,
                                                   unsigned short* __restrict__ Wb,
                                                   int rows) {
    int tid = blockIdx.x * 256 + threadIdx.x;
    if (tid >= rows * 64) return;
    int row = tid >> 6;
    int k   = (tid & 63) * 4;                 // chunk of 4, never straddles 128
    const float* src = (k < 128) ? (Ws + (size_t)row * 128 + k)
                                 : (Wn + (size_t)row * 128 + (k - 128));
    float4 v = *reinterpret_cast<const float4*>(src);
    uint2 o;
    o.x = (unsigned)f2bf(v.x) | ((unsigned)f2bf(v.y) << 16);
    o.y = (unsigned)f2bf(v.z) | ((unsigned)f2bf(v.w) << 16);
    *reinterpret_cast<uint2*>(Wb + (size_t)row * 256 + k) = o;
}

// ================= gather-mean aggregation (bf16 in/out, f32 accum) =========
// one wave per dst node; lane l holds features [2l, 2l+1] (4B packed bf16x2).
// 4-wide unroll = 4 independent row gathers in flight (MLP=4): proven R10,
// 67.5 -> <52.6 us.
__device__ __forceinline__ void bf2_acc(unsigned v, float& ax, float& ay) {
    ax += __uint_as_float(v << 16);
    ay += __uint_as_float(v & 0xFFFF0000u);
}

__global__ __launch_bounds__(256) void agg_kernel(const unsigned short* __restrict__ h,
                                                  const int* __restrict__ rp,
                                                  const int* __restrict__ col,
                                                  unsigned short* __restrict__ agg) {
    int w    = (blockIdx.x * 256 + threadIdx.x) >> 6;
    int lane = threadIdx.x & 63;
    if (w >= NN) return;
    int beg = __builtin_amdgcn_readfirstlane(rp[w]);
    int end = __builtin_amdgcn_readfirstlane(rp[w + 1]);
    const unsigned short* hl = h + lane * 2;
    float ax = 0.f, ay = 0.f;
    int e = beg;
    for (; e + 4 <= end; e += 4) {
        int s0 = col[e + 0], s1 = col[e + 1], s2 = col[e + 2], s3 = col[e + 3];
        unsigned v0 = *reinterpret_cast<const unsigned*>(hl + (size_t)s0 * FD);
        unsigned v1 = *reinterpret_cast<const unsigned*>(hl + (size_t)s1 * FD);
        unsigned v2 = *reinterpret_cast<const unsigned*>(hl + (size_t)s2 * FD);
        unsigned v3 = *reinterpret_cast<const unsigned*>(hl + (size_t)s3 * FD);
        bf2_acc(v0, ax, ay);
        bf2_acc(v1, ax, ay);
        bf2_acc(v2, ax, ay);
        bf2_acc(v3, ax, ay);
    }
    if (e + 2 <= end) {
        int s0 = col[e + 0], s1 = col[e + 1];
        unsigned v0 = *reinterpret_cast<const unsigned*>(hl + (size_t)s0 * FD);
        unsigned v1 = *reinterpret_cast<const unsigned*>(hl + (size_t)s1 * FD);
        bf2_acc(v0, ax, ay);
        bf2_acc(v1, ax, ay);
        e += 2;
    }
    if (e < end) {
        int s0 = col[e];
        unsigned v0 = *reinterpret_cast<const unsigned*>(hl + (size_t)s0 * FD);
        bf2_acc(v0, ax, ay);
    }
    float inv = 1.0f / fmaxf((float)(end - beg), 1.0f);
    ax *= inv;
    ay *= inv;
    *reinterpret_cast<unsigned*>(agg + (size_t)w * FD + lane * 2) =
        (unsigned)f2bf(ax) | ((unsigned)f2bf(ay) << 16);
}

// ================= MFMA SAGE GEMM (v4: zero-LDS, register-B) =================
// R10-R12 post-mortem: every LDS-staged variant sits at 40-55us with ALL
// pipes <10% busy — the stage/barrier/short-burst structure IS the cost.
// v4 exploits the MFMA fragment layout directly: A-frag = 16B/lane contiguous
// in k -> loadable straight from global h/agg (no LDS, no barriers). B (64KB,
// block-invariant) lives in REGISTERS: wave owns a 32-col slice = 16 bf16x8.
// NWC = N/32 col-slices: wave w -> cols (w%NWC)*32, rows (w/NWC)*16.
// Grid-stride over exact row tiles (NN % 32 == 0). Occupancy bounded only by
// VGPR (~115 -> 4 waves/SIMD); latency hidden by TLP+MLP (the R10 agg lever).
template <int NWC, bool RELU, bool OUTBF16, int OSTRIDE>
__global__ __launch_bounds__(256) void mfma_gemm(const unsigned short* __restrict__ Ah,
                                                 const unsigned short* __restrict__ Ag,
                                                 const unsigned short* __restrict__ Wb,
                                                 const float* __restrict__ bias,
                                                 void* __restrict__ outp) {
    constexpr int TR   = (4 / NWC) * 16;      // rows per block-iter: 16 or 32
    constexpr int NTIL = NN / TR;             // 6250 (NWC=4) or 3125 (NWC=2)

    const int t   = threadIdx.x;
    const int w   = t >> 6;
    const int l   = t & 63;
    const int lo4 = l & 15;
    const int hi  = l >> 4;
    const int jw      = (w % NWC) * 32;       // wave's col base
    const int row_off = (w / NWC) * 16;       // wave's row sub-tile

    // ---- B into registers: cols jw..jw+31, all 256 k. 16 x 16B loads ----
    bf16x8 breg[2][8];
#pragma unroll
    for (int f = 0; f < 2; ++f)
#pragma unroll
        for (int ks = 0; ks < 8; ++ks)
            breg[f][ks] = *reinterpret_cast<const bf16x8*>(
                Wb + (size_t)(jw + f * 16 + lo4) * 256 + ks * 32 + hi * 8);

    unsigned short* hout = (unsigned short*)outp;
    float* fout = (float*)outp;
    const float bv0 = bias[jw + lo4];
    const float bv1 = bias[jw + 16 + lo4];

    for (int tile = blockIdx.x; tile < NTIL; tile += gridDim.x) {
        const int row = tile * TR + row_off + lo4;
        const unsigned short* Ar = Ah + (size_t)row * FD;
        const unsigned short* Gr = Ag + (size_t)row * FD;
        // 8 independent 16B A-frag loads (ks 0-3 from h, 4-7 from agg)
        bf16x8 a[8];
#pragma unroll
        for (int ks = 0; ks < 4; ++ks)
            a[ks] = *reinterpret_cast<const bf16x8*>(Ar + ks * 32 + hi * 8);
#pragma unroll
        for (int ks = 0; ks < 4; ++ks)
            a[4 + ks] = *reinterpret_cast<const bf16x8*>(Gr + ks * 32 + hi * 8);

        f32x4 acc0 = {0.f, 0.f, 0.f, 0.f};
        f32x4 acc1 = {0.f, 0.f, 0.f, 0.f};
#pragma unroll
        for (int ks = 0; ks < 8; ++ks) {
            acc0 = __builtin_amdgcn_mfma_f32_16x16x32_bf16(a[ks], breg[0][ks], acc0, 0, 0, 0);
            acc1 = __builtin_amdgcn_mfma_f32_16x16x32_bf16(a[ks], breg[1][ks], acc1, 0, 0, 0);
        }

        // epilogue: C/D map col=l&15, row=(l>>4)*4+reg (m89)
        const int rbase = tile * TR + row_off + hi * 4;
#pragma unroll
        for (int r = 0; r < 4; ++r) {
            float v0 = acc0[r] + bv0;
            float v1 = acc1[r] + bv1;
            if (RELU) { v0 = fmaxf(v0, 0.f); v1 = fmaxf(v1, 0.f); }
            const size_t n = (size_t)(rbase + r);
            if (OUTBF16) {
                hout[n * OSTRIDE + jw + lo4]      = f2bf(v0);
                hout[n * OSTRIDE + jw + 16 + lo4] = f2bf(v1);
            } else {
                fout[n * OSTRIDE + jw + lo4]      = v0;
                fout[n * OSTRIDE + jw + 16 + lo4] = v1;
            }
        }
    }
}

extern "C" void kernel_launch(void* const* d_in, const int* in_sizes, int n_in,
                              void* d_out, int out_size, void* d_ws, size_t ws_size,
                              hipStream_t stream) {
    const float* x        = (const float*)d_in[0];
    const int*   edge_src = (const int*)d_in[1];
    const int*   edge_dst = (const int*)d_in[2];
    const float* Ws1 = (const float*)d_in[3];
    const float* Wn1 = (const float*)d_in[4];
    const float* b1  = (const float*)d_in[5];
    const float* Ws2 = (const float*)d_in[6];
    const float* Wn2 = (const float*)d_in[7];
    const float* b2  = (const float*)d_in[8];
    const float* Ws3 = (const float*)d_in[9];
    const float* Wn3 = (const float*)d_in[10];
    const float* b3  = (const float*)d_in[11];
    float* out = (float*)d_out;

    // ---- memory plan (d_ws == proven-safe 102.8 MB footprint) ----
    // d_ws : x_bf16 | h_a | h_b | agg (each NN*FD bf16 = 25.6MB) | cursor
    // d_out: col_src [NE] | row_ptr [NN+1] | pad | Wb1 | Wb2  (all reads
    //        complete before the final GEMM overwrites d_out)
    // Wb3 -> cursor region (dead after fill_kernel; wcvt3 runs after fill).
    // bsum aliases agg head (dead until first agg_kernel).
    unsigned short* x_bf = (unsigned short*)d_ws;
    unsigned short* h_a  = x_bf + (size_t)NN * FD;
    unsigned short* h_b  = h_a + (size_t)NN * FD;
    unsigned short* aggb = h_b + (size_t)NN * FD;
    int* cursor = (int*)(aggb + (size_t)NN * FD);
    int* bsum   = (int*)aggb;
    int* col_src = (int*)d_out;
    int* row_ptr = col_src + NE;
    unsigned short* wb1 = (unsigned short*)(col_src + NE + NN + 4);  // 16B-aligned
    unsigned short* wb2 = wb1 + 128 * 256;
    unsigned short* wb3 = (unsigned short*)cursor;                   // after fill

    const int edgeGrid = (NE + 255) / 256;
    const int aggGrid  = NN / 4;                         // 4 waves/block

    // ---- x -> bf16; weights -> packed bf16 ----
    cvt_kernel<<<(NN * FD / 4 + 255) / 256, 256, 0, stream>>>(x, x_bf, NN * FD / 4);
    wcvt_kernel<<<32, 256, 0, stream>>>(Ws1, Wn1, wb1, 128);
    wcvt_kernel<<<32, 256, 0, stream>>>(Ws2, Wn2, wb2, 128);

    // ---- CSR build ----
    hipMemsetAsync(cursor, 0, (size_t)NN * sizeof(int), stream);
    hist_kernel<<<edgeGrid, 256, 0, stream>>>(edge_dst, cursor, NE);
    scan_blocks<<<NB, 256, 0, stream>>>(cursor, bsum);
    scan_top<<<1, 512, 0, stream>>>(bsum, row_ptr);
    scan_write<<<NB, 256, 0, stream>>>(cursor, bsum, row_ptr);
    hipMemcpyAsync(cursor, row_ptr, (size_t)NN * sizeof(int),
                   hipMemcpyDeviceToDevice, stream);
    fill_kernel<<<edgeGrid, 256, 0, stream>>>(edge_src, edge_dst, cursor,
                                              col_src, NE);
    wcvt_kernel<<<16, 256, 0, stream>>>(Ws3, Wn3, wb3, 64);  // cursor now dead

    // ---- layer 1: x_bf -> h_a ----
    agg_kernel<<<aggGrid, 256, 0, stream>>>(x_bf, row_ptr, col_src, aggb);
    mfma_gemm<4, true, true, 128><<<1024, 256, 0, stream>>>(
        x_bf, aggb, wb1, b1, h_a);

    // ---- layer 2: h_a -> h_b ----
    agg_kernel<<<aggGrid, 256, 0, stream>>>(h_a, row_ptr, col_src, aggb);
    mfma_gemm<4, true, true, 128><<<1024, 256, 0, stream>>>(
        h_a, aggb, wb2, b2, h_b);

    // ---- layer 3: h_b -> out (f32, no ReLU; overwrites CSR+Wb in d_out) ----
    agg_kernel<<<aggGrid, 256, 0, stream>>>(h_b, row_ptr, col_src, aggb);
    mfma_gemm<2, false, false, 64><<<1024, 256, 0, stream>>>(
        h_b, aggb, wb3, b3, out);
}

// Round 14
// 363.867 us; speedup vs baseline: 1.2236x; 1.0058x over previous
//
#include <hip/hip_runtime.h>

#define NN 100000
#define NE 600000
#define FD 128                       // feature dim of h (in & hidden)
#define NB ((NN + 255) / 256)        // 391 scan blocks

typedef __attribute__((ext_vector_type(8))) short bf16x8;
typedef __attribute__((ext_vector_type(4))) float f32x4;

__device__ __forceinline__ unsigned short f2bf(float x) {
    unsigned int u = __float_as_uint(x);
    u += 0x7FFFu + ((u >> 16) & 1u);          // RNE
    return (unsigned short)(u >> 16);
}

// ================= CSR build (by destination) =================
__global__ __launch_bounds__(256) void hist_kernel(const int* __restrict__ dst,
                                                   int* __restrict__ cnt, int E) {
    int e = blockIdx.x * 256 + threadIdx.x;
    if (e < E) atomicAdd(&cnt[dst[e]], 1);
}

__global__ __launch_bounds__(256) void scan_blocks(const int* __restrict__ cnt,
                                                   int* __restrict__ bsum) {
    __shared__ int s[256];
    int i = blockIdx.x * 256 + threadIdx.x;
    int t = threadIdx.x;
    s[t] = (i < NN) ? cnt[i] : 0;
    __syncthreads();
    for (int off = 128; off > 0; off >>= 1) {
        if (t < off) s[t] += s[t + off];
        __syncthreads();
    }
    if (t == 0) bsum[blockIdx.x] = s[0];
}

__global__ __launch_bounds__(512) void scan_top(int* __restrict__ bsum,
                                                int* __restrict__ row_ptr) {
    __shared__ int s[512];
    int t = threadIdx.x;
    int v = (t < NB) ? bsum[t] : 0;
    s[t] = v;
    __syncthreads();
    for (int off = 1; off < 512; off <<= 1) {
        int x = (t >= off) ? s[t - off] : 0;
        __syncthreads();
        s[t] += x;
        __syncthreads();
    }
    if (t < NB) bsum[t] = s[t] - v;          // exclusive block offsets
    if (t == 0) row_ptr[NN] = NE;
}

__global__ __launch_bounds__(256) void scan_write(const int* __restrict__ cnt,
                                                  const int* __restrict__ bofs,
                                                  int* __restrict__ row_ptr) {
    __shared__ int s[256];
    int i = blockIdx.x * 256 + threadIdx.x;
    int t = threadIdx.x;
    int v = (i < NN) ? cnt[i] : 0;
    s[t] = v;
    __syncthreads();
    for (int off = 1; off < 256; off <<= 1) {
        int x = (t >= off) ? s[t - off] : 0;
        __syncthreads();
        s[t] += x;
        __syncthreads();
    }
    if (i < NN) row_ptr[i] = s[t] - v + bofs[blockIdx.x];
}

__global__ __launch_bounds__(256) void fill_kernel(const int* __restrict__ src,
                                                   const int* __restrict__ dst,
                                                   int* __restrict__ cursor,
                                                   int* __restrict__ col, int E) {
    int e = blockIdx.x * 256 + threadIdx.x;
    if (e < E) {
        int p = atomicAdd(&cursor[dst[e]], 1);
        col[p] = src[e];
    }
}

// ================= prep: x->bf16 + all 3 weight converts, ONE dispatch ======
// blocks [0,12500): x (NN*FD/4 uint2 chunks). Then 32+32+16 blocks for
// Wb1/Wb2/Wb3: Wb[j][0:256] = bf16([Ws|Wn][j]).
__device__ __forceinline__ void wcvt_body(const float* Ws, const float* Wn,
                                          unsigned short* Wb, int tid) {
    int row = tid >> 6;
    int k   = (tid & 63) * 4;                 // never straddles 128
    const float* src = (k < 128) ? (Ws + (size_t)row * 128 + k)
                                 : (Wn + (size_t)row * 128 + (k - 128));
    float4 v = *reinterpret_cast<const float4*>(src);
    uint2 o;
    o.x = (unsigned)f2bf(v.x) | ((unsigned)f2bf(v.y) << 16);
    o.y = (unsigned)f2bf(v.z) | ((unsigned)f2bf(v.w) << 16);
    *reinterpret_cast<uint2*>(Wb + (size_t)row * 256 + k) = o;
}

__global__ __launch_bounds__(256) void prep_kernel(const float* __restrict__ x,
                                                   unsigned short* __restrict__ xb,
                                                   const float* __restrict__ Ws1,
                                                   const float* __restrict__ Wn1,
                                                   unsigned short* __restrict__ Wb1,
                                                   const float* __restrict__ Ws2,
                                                   const float* __restrict__ Wn2,
                                                   unsigned short* __restrict__ Wb2,
                                                   const float* __restrict__ Ws3,
                                                   const float* __restrict__ Wn3,
                                                   unsigned short* __restrict__ Wb3) {
    int b = blockIdx.x;
    int t = threadIdx.x;
    if (b < 12500) {                          // x convert: 12500*256 == NN*FD/4
        int i = b * 256 + t;
        float4 v = reinterpret_cast<const float4*>(x)[i];
        uint2 o;
        o.x = (unsigned)f2bf(v.x) | ((unsigned)f2bf(v.y) << 16);
        o.y = (unsigned)f2bf(v.z) | ((unsigned)f2bf(v.w) << 16);
        reinterpret_cast<uint2*>(xb)[i] = o;
    } else if (b < 12532) {
        wcvt_body(Ws1, Wn1, Wb1, (b - 12500) * 256 + t);
    } else if (b < 12564) {
        wcvt_body(Ws2, Wn2, Wb2, (b - 12532) * 256 + t);
    } else {
        wcvt_body(Ws3, Wn3, Wb3, (b - 12564) * 256 + t);
    }
}

// ================= gather-mean aggregation (bf16 in/out, f32 accum) =========
// one wave per dst node; lane l holds features [2l, 2l+1] (4B packed bf16x2).
// R8->R10: MLP=4 unroll cut 67.5 -> ~37us (latency-bound). R14: MLP=8 via
// clamped-index streams (idx=min(e+i,last), zero-masked) — no tail branches,
// 8 gathers in flight; dead clamped loads are L1-hot.
__global__ __launch_bounds__(256) void agg_kernel(const unsigned short* __restrict__ h,
                                                  const int* __restrict__ rp,
                                                  const int* __restrict__ col,
                                                  unsigned short* __restrict__ agg) {
    int w    = (blockIdx.x * 256 + threadIdx.x) >> 6;
    int lane = threadIdx.x & 63;
    if (w >= NN) return;
    int beg = __builtin_amdgcn_readfirstlane(rp[w]);
    int end = __builtin_amdgcn_readfirstlane(rp[w + 1]);
    const unsigned short* hl = h + lane * 2;
    float ax = 0.f, ay = 0.f;
    if (beg < end) {
        int last = end - 1;
        for (int e = beg; e < end; e += 8) {
#pragma unroll
            for (int i = 0; i < 8; ++i) {
                int ee  = e + i;
                int idx = col[ee <= last ? ee : last];
                unsigned v = *reinterpret_cast<const unsigned*>(hl + (size_t)idx * FD);
                if (ee > last) v = 0u;
                ax += __uint_as_float(v << 16);
                ay += __uint_as_float(v & 0xFFFF0000u);
            }
        }
    }
    float inv = 1.0f / fmaxf((float)(end - beg), 1.0f);
    ax *= inv;
    ay *= inv;
    *reinterpret_cast<unsigned*>(agg + (size_t)w * FD + lane * 2) =
        (unsigned)f2bf(ax) | ((unsigned)f2bf(ay) << 16);
}

// ================= MFMA SAGE GEMM (v5: zero-LDS reg-B, paired-col stores) ====
// v4 (R13): no LDS/barriers; B in registers; ~40us/layer, bound by A-read +
// store memory path. v5 keeps the structure and halves store instructions:
// wave loads B rows (jw + 2*lo4 + f), f=0,1 -> acc0/acc1 are ADJACENT output
// cols -> one packed 4B (bf16) / 8B (f32) store per row. 256B+ contiguous
// segments per store instr (was 2B scattered x8).
template <int NWC, bool RELU, bool OUTBF16, int OSTRIDE>
__global__ __launch_bounds__(256) void mfma_gemm(const unsigned short* __restrict__ Ah,
                                                 const unsigned short* __restrict__ Ag,
                                                 const unsigned short* __restrict__ Wb,
                                                 const float* __restrict__ bias,
                                                 void* __restrict__ outp) {
    constexpr int TR   = (4 / NWC) * 16;      // rows per block-iter: 16 or 32
    constexpr int NTIL = NN / TR;             // 6250 (NWC=4) or 3125 (NWC=2)

    const int t   = threadIdx.x;
    const int w   = t >> 6;
    const int l   = t & 63;
    const int lo4 = l & 15;
    const int hi  = l >> 4;
    const int jw      = (w % NWC) * 32;       // wave's col base
    const int row_off = (w / NWC) * 16;       // wave's row sub-tile

    // ---- B into registers: wave's col-slot lo4 = output cols jw+2*lo4+f ----
    bf16x8 breg[2][8];
#pragma unroll
    for (int f = 0; f < 2; ++f)
#pragma unroll
        for (int ks = 0; ks < 8; ++ks)
            breg[f][ks] = *reinterpret_cast<const bf16x8*>(
                Wb + (size_t)(jw + 2 * lo4 + f) * 256 + ks * 32 + hi * 8);

    unsigned short* hout = (unsigned short*)outp;
    float* fout = (float*)outp;
    const float bv0 = bias[jw + 2 * lo4];
    const float bv1 = bias[jw + 2 * lo4 + 1];

    for (int tile = blockIdx.x; tile < NTIL; tile += gridDim.x) {
        const int row = tile * TR + row_off + lo4;
        const unsigned short* Ar = Ah + (size_t)row * FD;
        const unsigned short* Gr = Ag + (size_t)row * FD;
        // 8 independent 16B A-frag loads (ks 0-3 from h, 4-7 from agg)
        bf16x8 a[8];
#pragma unroll
        for (int ks = 0; ks < 4; ++ks)
            a[ks] = *reinterpret_cast<const bf16x8*>(Ar + ks * 32 + hi * 8);
#pragma unroll
        for (int ks = 0; ks < 4; ++ks)
            a[4 + ks] = *reinterpret_cast<const bf16x8*>(Gr + ks * 32 + hi * 8);

        f32x4 acc0 = {0.f, 0.f, 0.f, 0.f};
        f32x4 acc1 = {0.f, 0.f, 0.f, 0.f};
#pragma unroll
        for (int ks = 0; ks < 8; ++ks) {
            acc0 = __builtin_amdgcn_mfma_f32_16x16x32_bf16(a[ks], breg[0][ks], acc0, 0, 0, 0);
            acc1 = __builtin_amdgcn_mfma_f32_16x16x32_bf16(a[ks], breg[1][ks], acc1, 0, 0, 0);
        }

        // epilogue: C/D row=(l>>4)*4+r, col-slot=lo4 -> cols jw+2*lo4+{0,1}
        const int rbase = tile * TR + row_off + hi * 4;
#pragma unroll
        for (int r = 0; r < 4; ++r) {
            float v0 = acc0[r] + bv0;
            float v1 = acc1[r] + bv1;
            if (RELU) { v0 = fmaxf(v0, 0.f); v1 = fmaxf(v1, 0.f); }
            const size_t n = (size_t)(rbase + r);
            if (OUTBF16) {
                unsigned pk = (unsigned)f2bf(v0) | ((unsigned)f2bf(v1) << 16);
                *reinterpret_cast<unsigned*>(hout + n * OSTRIDE + jw + 2 * lo4) = pk;
            } else {
                *reinterpret_cast<float2*>(fout + n * OSTRIDE + jw + 2 * lo4) =
                    make_float2(v0, v1);
            }
        }
    }
}

extern "C" void kernel_launch(void* const* d_in, const int* in_sizes, int n_in,
                              void* d_out, int out_size, void* d_ws, size_t ws_size,
                              hipStream_t stream) {
    const float* x        = (const float*)d_in[0];
    const int*   edge_src = (const int*)d_in[1];
    const int*   edge_dst = (const int*)d_in[2];
    const float* Ws1 = (const float*)d_in[3];
    const float* Wn1 = (const float*)d_in[4];
    const float* b1  = (const float*)d_in[5];
    const float* Ws2 = (const float*)d_in[6];
    const float* Wn2 = (const float*)d_in[7];
    const float* b2  = (const float*)d_in[8];
    const float* Ws3 = (const float*)d_in[9];
    const float* Wn3 = (const float*)d_in[10];
    const float* b3  = (const float*)d_in[11];
    float* out = (float*)d_out;

    // ---- memory plan: everything in d_ws (268 MB actual, per R13 PMC;
    //      usage ~106 MB). No d_out aliasing games.
    unsigned short* x_bf = (unsigned short*)d_ws;
    unsigned short* h_a  = x_bf + (size_t)NN * FD;
    unsigned short* h_b  = h_a + (size_t)NN * FD;
    unsigned short* aggb = h_b + (size_t)NN * FD;
    unsigned short* wb1  = aggb + (size_t)NN * FD;       // 64KB
    unsigned short* wb2  = wb1 + 128 * 256;              // 64KB
    unsigned short* wb3  = wb2 + 128 * 256;              // 32KB
    int* cursor  = (int*)(wb3 + 64 * 256);
    int* col_src = cursor + NN;
    int* row_ptr = col_src + NE;
    int* bsum    = row_ptr + (NN + 1);

    const int edgeGrid = (NE + 255) / 256;
    const int aggGrid  = NN / 4;                         // 4 waves/block

    // ---- prep: x->bf16 + Wb1/2/3 in ONE dispatch ----
    prep_kernel<<<12580, 256, 0, stream>>>(x, x_bf, Ws1, Wn1, wb1,
                                           Ws2, Wn2, wb2, Ws3, Wn3, wb3);

    // ---- CSR build ----
    hipMemsetAsync(cursor, 0, (size_t)NN * sizeof(int), stream);
    hist_kernel<<<edgeGrid, 256, 0, stream>>>(edge_dst, cursor, NE);
    scan_blocks<<<NB, 256, 0, stream>>>(cursor, bsum);
    scan_top<<<1, 512, 0, stream>>>(bsum, row_ptr);
    scan_write<<<NB, 256, 0, stream>>>(cursor, bsum, row_ptr);
    hipMemcpyAsync(cursor, row_ptr, (size_t)NN * sizeof(int),
                   hipMemcpyDeviceToDevice, stream);
    fill_kernel<<<edgeGrid, 256, 0, stream>>>(edge_src, edge_dst, cursor,
                                              col_src, NE);

    // ---- layer 1: x_bf -> h_a ----
    agg_kernel<<<aggGrid, 256, 0, stream>>>(x_bf, row_ptr, col_src, aggb);
    mfma_gemm<4, true, true, 128><<<1024, 256, 0, stream>>>(
        x_bf, aggb, wb1, b1, h_a);

    // ---- layer 2: h_a -> h_b ----
    agg_kernel<<<aggGrid, 256, 0, stream>>>(h_a, row_ptr, col_src, aggb);
    mfma_gemm<4, true, true, 128><<<1024, 256, 0, stream>>>(
        h_a, aggb, wb2, b2, h_b);

    // ---- layer 3: h_b -> out (f32, no ReLU) ----
    agg_kernel<<<aggGrid, 256, 0, stream>>>(h_b, row_ptr, col_src, aggb);
    mfma_gemm<2, false, false, 64><<<1024, 256, 0, stream>>>(
        h_b, aggb, wb3, b3, out);
}